// Round 1
// baseline (102.260 us; speedup 1.0000x reference)
//
#include <hip/hip_runtime.h>
#include <cstdint>
#include <cmath>

// ---------------------------------------------------------------------------
// KDNet: 11x fused { pointwise conv + ReLU + kd-gather + pair-maxpool }, then
// FC(1024->16) + log_softmax.  Multi-launch structure (cooperative grid.sync
// measured ~100us/sync on 8 XCDs — 6x worse; do not revisit).
//
//   e = 3d + sel[d]; q = e/dim; p = e%dim   (batch-uniform per position d)
//   pre[b,f,d] = dot(W[3f+q,:], x[b,:,p]) + bias[3f+q]
//   out[b,f,j] = relu(max(pre[.,.,2j], pre[.,.,2j+1]))
//
// Structure this round:
//   l01      : fused L0+L1 (+wprep for W6..W10)            -> actB [B,512,32]
//   chain    : L2..L5 fused, 1 block per batch row, all     -> actA [B,32,128]
//              activations in an aliased 80KB LDS pool, 3q-brute-force MFMA
//              (q varies per gathered row; compute q=0,1,2 tiles, select per
//              acc row in epilogue; pair-max is in-lane since acc rows 4g+i
//              pair (2j,2j+1)).  XOR slot swizzle on all LDS tiles.
//   L6..L10  : unified kdmfma template (unchanged)
//   fc_lsm   : FC + log_softmax (unchanged)
// ---------------------------------------------------------------------------

typedef __attribute__((ext_vector_type(8))) short bhalf8;
typedef __attribute__((ext_vector_type(4))) float floatx4;

__device__ __forceinline__ unsigned short f2bf(float f) {
    uint32_t u = __float_as_uint(f);
    u += 0x7FFFu + ((u >> 16) & 1u);          // round-to-nearest-even
    return (unsigned short)(u >> 16);
}
__device__ __forceinline__ float bf2f(unsigned short u) {
    return __uint_as_float(((uint32_t)u) << 16);
}

struct WPrep {
    const float* src[9];
    unsigned short* dst[9];
    int n4[9];
};

// ---- fused L0+L1 (+wprep in blocks >= nL1): x [B,3,2048] -> [B,512,32] bf16
__global__ __launch_bounds__(256)
void l01_kernel(const float* __restrict__ x,
                const float* __restrict__ W0, const float* __restrict__ b0,
                const int* __restrict__ sel0,
                const float* __restrict__ W1, const float* __restrict__ b1,
                const int* __restrict__ sel1,
                unsigned short* __restrict__ out,
                WPrep wp, int nL1) {
    const int tid = threadIdx.x;

    if ((int)blockIdx.x >= nL1) {              // ---- weight-prep blocks ----
        const int stride = (gridDim.x - nL1) * 256;
        const int g0 = (blockIdx.x - nL1) * 256 + tid;
        #pragma unroll
        for (int l = 0; l < 5; ++l) {          // W6..W10 only
            const float4* s = reinterpret_cast<const float4*>(wp.src[l]);
            uint2* d = reinterpret_cast<uint2*>(wp.dst[l]);
            for (int i = g0; i < wp.n4[l]; i += stride) {
                const float4 v = s[i];
                uint2 o;
                o.x = (uint32_t)f2bf(v.x) | ((uint32_t)f2bf(v.y) << 16);
                o.y = (uint32_t)f2bf(v.z) | ((uint32_t)f2bf(v.w) << 16);
                d[i] = o;
            }
        }
        return;
    }

    __shared__ float W0s[24][3]; __shared__ float b0s[24];
    __shared__ float W1s[96][8]; __shared__ float b1s[96];
    if (tid < 24) {
        W0s[tid][0] = W0[tid * 3 + 0];
        W0s[tid][1] = W0[tid * 3 + 1];
        W0s[tid][2] = W0[tid * 3 + 2];
        b0s[tid] = b0[tid];
    }
    if (tid < 96) {
        #pragma unroll
        for (int k = 0; k < 8; ++k) W1s[tid][k] = W1[tid * 8 + k];
        b1s[tid] = b1[tid];
    }
    __syncthreads();

    const int gid = blockIdx.x * 256 + tid;
    const int b  = gid >> 9;
    const int j1 = gid & 511;
    const float* xb = x + (size_t)b * 3 * 2048;

    float cols[2][8];     // L0 output columns for L1's two gathered positions
    int q1v[2];
    #pragma unroll
    for (int pos1 = 0; pos1 < 2; ++pos1) {
        const int d1 = 2 * j1 + pos1;
        const int e1 = 3 * d1 + sel1[d1];
        const int q1 = (e1 >= 1024) + (e1 >= 2048);
        const int p1 = e1 - q1 * 1024;         // L0 output position
        q1v[pos1] = q1;

        float xv[2][3]; int qq0[2];
        #pragma unroll
        for (int pos0 = 0; pos0 < 2; ++pos0) {
            const int d0 = 2 * p1 + pos0;
            const int e0 = 3 * d0 + sel0[d0];
            const int q0 = (e0 >= 2048) + (e0 >= 4096);
            const int p0 = e0 - q0 * 2048;
            qq0[pos0] = q0;
            xv[pos0][0] = xb[p0];
            xv[pos0][1] = xb[2048 + p0];
            xv[pos0][2] = xb[4096 + p0];
        }
        #pragma unroll
        for (int f = 0; f < 8; ++f) {
            const int r0 = 3 * f + qq0[0], r1 = 3 * f + qq0[1];
            const float v0 = b0s[r0] + W0s[r0][0]*xv[0][0] + W0s[r0][1]*xv[0][1] + W0s[r0][2]*xv[0][2];
            const float v1 = b0s[r1] + W0s[r1][0]*xv[1][0] + W0s[r1][1]*xv[1][1] + W0s[r1][2]*xv[1][2];
            cols[pos1][f] = fmaxf(fmaxf(v0, v1), 0.f);
        }
    }

    unsigned short o[32];
    #pragma unroll
    for (int f = 0; f < 32; ++f) {
        const int r0 = 3 * f + q1v[0], r1 = 3 * f + q1v[1];
        float v0 = b1s[r0], v1 = b1s[r1];
        #pragma unroll
        for (int k = 0; k < 8; ++k) {
            v0 = fmaf(cols[0][k], W1s[r0][k], v0);
            v1 = fmaf(cols[1][k], W1s[r1][k], v1);
        }
        o[f] = f2bf(fmaxf(fmaxf(v0, v1), 0.f));
    }
    bhalf8* op = reinterpret_cast<bhalf8*>(out + (size_t)gid * 32);
    #pragma unroll
    for (int i = 0; i < 4; ++i) {
        bhalf8 v;
        #pragma unroll
        for (int k = 0; k < 8; ++k) v[k] = (short)o[8*i + k];
        op[i] = v;
    }
}

// ---------------------------------------------------------------------------
// chain: L2..L5 fused, one block per batch row.
// LDS pool (79872 B -> 2 blocks/CU) with per-phase aliased regions:
//   L2: IN[0,32K) W2[32K,44K) m2@45056 O2[47104,79872)
//   L3: in=O2     O3[0,16K)   W3[16K,40K)  m3@40960
//   L4: in=O3     O4[16K,24K) W4[24K,48K)  m4@49152
//   L5: in=O4     O5[0,8K)    W5[24K,72K)  m5@73728
// XOR slot swizzle (byte ^= (row&SM)<<4) on every LDS tile, applied on both
// write and read side (removes the 8..16-way ds_read_b128 bank conflicts
// that row-major stride-64/128B tiles would have).
// ---------------------------------------------------------------------------

template<int RB>
__device__ __forceinline__ int swaddr(int row, int colbyte) {
    constexpr int SM = (RB / 16 >= 8) ? 7 : (RB / 16 - 1);
    return row * RB + (colbyte ^ ((row & SM) << 4));
}

template<int DIM, int CIN, int FEAT>
__device__ __forceinline__ void kdlayer(char* pool, int offIn, int offOut,
                                        int offW, int offMisc,
                                        const float* __restrict__ Wg,
                                        const float* __restrict__ bg,
                                        const int* __restrict__ sel, int tid) {
    constexpr int NH  = CIN / 32;      // mfma k-slices
    constexpr int MT  = DIM / 16;      // M tiles (gathered rows)
    constexpr int NT  = FEAT / 16;     // N tiles
    constexpr int RBW = CIN * 2;       // row bytes, input/weight tiles
    constexpr int RBO = FEAT * 2;      // row bytes, output tile
    float* biasS = (float*)(pool + offMisc);
    unsigned short* qp = (unsigned short*)(pool + offMisc + 3 * FEAT * 4);

    // stage W: fp32 -> bf16, swizzled rows of CIN
    {
        constexpr int NW4 = 3 * FEAT * CIN / 4;
        const float4* Ws = (const float4*)Wg;
        for (int i = tid; i < NW4; i += 256) {
            const float4 v = Ws[i];
            const int row = (i * 4) / CIN, col = (i * 4) % CIN;
            uint2 o;
            o.x = (uint32_t)f2bf(v.x) | ((uint32_t)f2bf(v.y) << 16);
            o.y = (uint32_t)f2bf(v.z) | ((uint32_t)f2bf(v.w) << 16);
            *(uint2*)(pool + offW + swaddr<RBW>(row, col * 2)) = o;
        }
    }
    for (int i = tid; i < 3 * FEAT; i += 256) biasS[i] = bg[i];
    for (int d = tid; d < DIM; d += 256) {
        const int e = 3 * d + sel[d];
        const int q = (e >= DIM) + (e >= 2 * DIM);
        qp[d] = (unsigned short)((q << 12) | (e - q * DIM));
    }
    __syncthreads();

    const int lane = tid & 63, wave = tid >> 6;
    const int g = lane >> 4, l15 = lane & 15;
    for (int mt = wave; mt < MT; mt += 4) {
        const int pa = qp[mt * 16 + l15] & 0xFFF;    // A row -> position
        bhalf8 aF[NH];
        #pragma unroll
        for (int ks = 0; ks < NH; ++ks)
            aF[ks] = *(const bhalf8*)(pool + offIn +
                        swaddr<RBW>(pa, (ks * 32 + g * 8) * 2));
        const int r0 = mt * 16 + g * 4;              // this lane's acc rows
        int qv[4];
        #pragma unroll
        for (int i = 0; i < 4; ++i) qv[i] = qp[r0 + i] >> 12;
        const int j0 = mt * 8 + g * 2;               // output row pair base
        #pragma unroll
        for (int nt = 0; nt < NT; ++nt) {
            const int f = nt * 16 + l15;
            floatx4 acc[3];
            #pragma unroll
            for (int q = 0; q < 3; ++q) acc[q] = (floatx4){0.f, 0.f, 0.f, 0.f};
            #pragma unroll
            for (int q = 0; q < 3; ++q)
                #pragma unroll
                for (int ks = 0; ks < NH; ++ks) {
                    const bhalf8 bF = *(const bhalf8*)(pool + offW +
                        swaddr<RBW>(3 * f + q, (ks * 32 + g * 8) * 2));
                    acc[q] = __builtin_amdgcn_mfma_f32_16x16x32_bf16(
                        aF[ks], bF, acc[q], 0, 0, 0);
                }
            float v[4];
            #pragma unroll
            for (int i = 0; i < 4; ++i) {
                const float a0 = acc[0][i], a1 = acc[1][i], a2 = acc[2][i];
                const int qi = qv[i];
                const float pre = (qi == 0) ? a0 : (qi == 1 ? a1 : a2);
                v[i] = pre + biasS[3 * f + qi];
            }
            *(unsigned short*)(pool + offOut + swaddr<RBO>(j0, f * 2)) =
                f2bf(fmaxf(fmaxf(v[0], v[1]), 0.f));
            *(unsigned short*)(pool + offOut + swaddr<RBO>(j0 + 1, f * 2)) =
                f2bf(fmaxf(fmaxf(v[2], v[3]), 0.f));
        }
    }
    __syncthreads();
}

__global__ __launch_bounds__(256)
void chain_kernel(const unsigned short* __restrict__ act,   // [B,512,32] bf16
                  unsigned short* __restrict__ out,         // [B,32,128] bf16
                  const float* __restrict__ W2, const float* __restrict__ b2, const int* __restrict__ s2,
                  const float* __restrict__ W3, const float* __restrict__ b3, const int* __restrict__ s3,
                  const float* __restrict__ W4, const float* __restrict__ b4, const int* __restrict__ s4,
                  const float* __restrict__ W5, const float* __restrict__ b5, const int* __restrict__ s5) {
    __shared__ __align__(16) char pool[79872];
    const int tid = threadIdx.x;
    const int b = blockIdx.x;

    // stage input [512][32] bf16 (RB=64), coalesced, swizzled
    {
        const char* src = (const char*)(act + (size_t)b * 512 * 32);
        #pragma unroll
        for (int k = 0; k < 8; ++k) {
            const int off = tid * 16 + k * 4096;
            const bhalf8 v = *(const bhalf8*)(src + off);
            *(bhalf8*)(pool + swaddr<64>(off >> 6, off & 63)) = v;
        }
    }

    kdlayer<512, 32,  64>(pool, 0,     47104, 32768, 45056, W2, b2, s2, tid);
    kdlayer<256, 64,  64>(pool, 47104, 0,     16384, 40960, W3, b3, s3, tid);
    kdlayer<128, 64,  64>(pool, 0,     16384, 24576, 49152, W4, b4, s4, tid);
    kdlayer< 64, 64, 128>(pool, 16384, 0,     24576, 73728, W5, b5, s5, tid);

    // write out [32][128] bf16 (RB=256), coalesced, unswizzle on read
    {
        char* dst = (char*)(out + (size_t)b * 32 * 128);
        #pragma unroll
        for (int k = 0; k < 2; ++k) {
            const int off = tid * 16 + k * 4096;
            const bhalf8 v = *(const bhalf8*)(pool + swaddr<256>(off >> 8, off & 255));
            *(bhalf8*)(dst + off) = v;
        }
    }
}

// ---------------------------------------------------------------------------
// Unified bf16 MFMA GEMM layer (bf16 act in, bf16 act out, bf16 W).
// Tile: BT rows x 64 feats. KS = min(CIN,128).   (L6..L10)
// ---------------------------------------------------------------------------
template<int CIN, int BT>
__global__ __launch_bounds__(256)
void kdmfma_kernel(const unsigned short* __restrict__ act,
                   const unsigned short* __restrict__ Wq,
                   const float* __restrict__ bias,
                   const int*   __restrict__ sel,
                   unsigned short* __restrict__ out,
                   int feat, int dim, int nbt) {
    constexpr int KS  = (CIN >= 128) ? 128 : CIN;
    constexpr int NH  = KS / 32;              // mfma k-slices per stage
    constexpr int LDK = KS + 8;
    constexpr int TPA = 256 / BT;             // threads per A row
    constexpr int EA  = KS / TPA;             // A elems per thread (mult of 8)
    constexpr int NSA = EA / 8;               // bhalf8 per thread (A)
    constexpr int NSW = KS / 32;              // bhalf8 per thread (W, 64 rows)
    constexpr int MF  = 2;                    // frag rows per wave
    constexpr int NF  = (BT == 64) ? 2 : 1;   // frag cols per wave
    __shared__ __align__(16) unsigned short Ab[BT][LDK];
    __shared__ __align__(16) unsigned short Wb[64][LDK];

    const int dimh = dim >> 1;
    const int bt = blockIdx.x % nbt;
    const int j  = blockIdx.x / nbt;
    const int f0 = blockIdx.y * 64;
    const int b0 = bt * BT;

    const int tid  = threadIdx.x;
    const int lane = tid & 63;
    const int wave = tid >> 6;

    const int srowA = tid / TPA;
    const int kgA   = (tid % TPA) * EA;
    const int srowW = tid >> 2;
    const int kgW   = (tid & 3) * (KS / 4);

    const int rowBase = (BT == 64) ? (wave & 1) * 32 : 0;
    const int colBase = (BT == 64) ? (wave >> 1) * 32 : wave * 16;

    floatx4 acc[2][MF][NF];
    #pragma unroll
    for (int pp = 0; pp < 2; ++pp)
        #pragma unroll
        for (int mi = 0; mi < MF; ++mi)
            #pragma unroll
            for (int ni = 0; ni < NF; ++ni)
                acc[pp][mi][ni] = (floatx4){0.f, 0.f, 0.f, 0.f};
    int qv[2];

    #pragma unroll
    for (int pp = 0; pp < 2; ++pp) {
        const int d = 2 * j + pp;
        const int s = sel[d];
        const int e = 3 * d + s;
        const int q = (e >= dim) + (e >= 2 * dim);
        const int p = e - q * dim;
        qv[pp] = q;

        const unsigned short* Ap = act + ((size_t)(b0 + srowA) * dim + p) * CIN + kgA;
        const unsigned short* Wp = Wq + ((size_t)(3 * (f0 + srowW) + q)) * CIN + kgW;

        bhalf8 pa[NSA], pw[NSW];
        #pragma unroll
        for (int u = 0; u < NSA; ++u)
            pa[u] = *reinterpret_cast<const bhalf8*>(Ap + u * 8);
        #pragma unroll
        for (int u = 0; u < NSW; ++u)
            pw[u] = *reinterpret_cast<const bhalf8*>(Wp + u * 8);

        for (int k0 = 0; k0 < CIN; k0 += KS) {
            __syncthreads();   // prior stage's fragment reads complete
            #pragma unroll
            for (int u = 0; u < NSA; ++u)
                *reinterpret_cast<bhalf8*>(&Ab[srowA][kgA + u * 8]) = pa[u];
            #pragma unroll
            for (int u = 0; u < NSW; ++u)
                *reinterpret_cast<bhalf8*>(&Wb[srowW][kgW + u * 8]) = pw[u];
            if (k0 + KS < CIN) {   // prefetch next stage
                #pragma unroll
                for (int u = 0; u < NSA; ++u)
                    pa[u] = *reinterpret_cast<const bhalf8*>(Ap + k0 + KS + u * 8);
                #pragma unroll
                for (int u = 0; u < NSW; ++u)
                    pw[u] = *reinterpret_cast<const bhalf8*>(Wp + k0 + KS + u * 8);
            }
            __syncthreads();

            #pragma unroll
            for (int ks = 0; ks < NH; ++ks) {
                const int kk = ks * 32 + (lane >> 4) * 8;
                bhalf8 aF[MF], bF[NF];
                #pragma unroll
                for (int mi = 0; mi < MF; ++mi)
                    aF[mi] = *reinterpret_cast<const bhalf8*>(
                        &Ab[rowBase + mi * 16 + (lane & 15)][kk]);
                #pragma unroll
                for (int ni = 0; ni < NF; ++ni)
                    bF[ni] = *reinterpret_cast<const bhalf8*>(
                        &Wb[colBase + ni * 16 + (lane & 15)][kk]);
                #pragma unroll
                for (int mi = 0; mi < MF; ++mi)
                    #pragma unroll
                    for (int ni = 0; ni < NF; ++ni)
                        acc[pp][mi][ni] = __builtin_amdgcn_mfma_f32_16x16x32_bf16(
                            aF[mi], bF[ni], acc[pp][mi][ni], 0, 0, 0);
            }
        }
    }

    const int orow = (lane >> 4) << 2;
    const int ocol = lane & 15;
    #pragma unroll
    for (int mi = 0; mi < MF; ++mi)
        #pragma unroll
        for (int ni = 0; ni < NF; ++ni) {
            const int fc = f0 + colBase + ni * 16 + ocol;
            const float bv0 = bias[3 * fc + qv[0]];
            const float bv1 = bias[3 * fc + qv[1]];
            #pragma unroll
            for (int i = 0; i < 4; ++i) {
                const int br = b0 + rowBase + mi * 16 + orow + i;
                const float v = fmaxf(fmaxf(acc[0][mi][ni][i] + bv0,
                                            acc[1][mi][ni][i] + bv1), 0.f);
                out[((size_t)br * dimh + j) * feat + fc] = f2bf(v);
            }
        }
}

// FC (1024 -> 16) + log_softmax; input bf16 [B, 1024].
__global__ __launch_bounds__(256)
void fc_lsm_kernel(const unsigned short* __restrict__ y,
                   const float* __restrict__ Wfc,
                   const float* __restrict__ bfc,
                   float* __restrict__ out) {
    const int b   = blockIdx.x;
    const int tid = threadIdx.x;
    __shared__ __align__(16) float ys[1024];
    __shared__ float lg[16];

    {
        const ushort4 v = reinterpret_cast<const ushort4*>(y + (size_t)b * 1024)[tid];
        ys[tid * 4 + 0] = bf2f(v.x);
        ys[tid * 4 + 1] = bf2f(v.y);
        ys[tid * 4 + 2] = bf2f(v.z);
        ys[tid * 4 + 3] = bf2f(v.w);
    }
    __syncthreads();

    const int l = tid >> 4, lane = tid & 15;
    const float4* w4 = reinterpret_cast<const float4*>(Wfc + (size_t)l * 1024);
    const float4* y4 = reinterpret_cast<const float4*>(ys);
    float p = 0.f;
    #pragma unroll
    for (int i = 0; i < 16; ++i) {
        const float4 a = y4[lane + 16 * i];
        const float4 w = w4[lane + 16 * i];
        p += a.x * w.x + a.y * w.y + a.z * w.z + a.w * w.w;
    }
    #pragma unroll
    for (int off = 8; off > 0; off >>= 1) p += __shfl_down(p, off, 16);
    if (lane == 0) lg[l] = p + bfc[l];
    __syncthreads();

    if (tid < 16) {
        float m = -1e30f;
        #pragma unroll
        for (int i = 0; i < 16; ++i) m = fmaxf(m, lg[i]);
        float s = 0.f;
        #pragma unroll
        for (int i = 0; i < 16; ++i) s += expf(lg[i] - m);
        out[b * 16 + tid] = lg[tid] - m - logf(s);
    }
}

extern "C" void kernel_launch(void* const* d_in, const int* in_sizes, int n_in,
                              void* d_out, int out_size, void* d_ws, size_t ws_size,
                              hipStream_t stream) {
    static const int LFEAT[11] = {8, 32, 64, 64, 64, 128, 256, 512, 512, 512, 1024};
    static const int LDIM[11]  = {2048, 1024, 512, 256, 128, 64, 32, 16, 8, 4, 2};
    static const int LCIN[11]  = {3, 8, 32, 64, 64, 64, 128, 256, 512, 512, 512};

    const float* x = (const float*)d_in[0];
    const int B = in_sizes[0] / (3 * 2048);   // 512

    const size_t slot = (size_t)B * 32 * 512;   // floats
    float* bufA = (float*)d_ws;
    float* bufB = bufA + slot;
    unsigned short* wq = (unsigned short*)(bufB + slot);

    const float* W[11]; const float* bi[11]; const int* sl[11];
    for (int i = 0; i < 11; ++i) {
        W[i]  = (const float*)d_in[12 + 2 * i];
        bi[i] = (const float*)d_in[13 + 2 * i];
        sl[i] = (const int*)d_in[1 + i];
    }

    unsigned short* wqp[11];
    {
        size_t off = 0;
        for (int i = 6; i <= 10; ++i) {
            wqp[i] = wq + off;
            off += (size_t)3 * LFEAT[i] * LCIN[i];
        }
    }

    unsigned short* actA = (unsigned short*)bufA;
    unsigned short* actB = (unsigned short*)bufB;

    // fused L0+L1 (+wprep blocks for W6..W10) -> actB
    {
        WPrep wp;
        for (int i = 6; i <= 10; ++i) {
            wp.src[i - 6] = W[i];
            wp.dst[i - 6] = wqp[i];
            wp.n4[i - 6]  = (3 * LFEAT[i] * LCIN[i]) / 4;
        }
        for (int l = 5; l < 9; ++l) { wp.src[l] = nullptr; wp.dst[l] = nullptr; wp.n4[l] = 0; }
        const int nL1 = (B * 512) / 256;   // 1024
        l01_kernel<<<nL1 + 768, 256, 0, stream>>>(x, W[0], bi[0], sl[0],
                                                  W[1], bi[1], sl[1],
                                                  actB, wp, nL1);
    }

    // L2..L5 fused chain: actB [B,512,32] -> actA [B,32,128]
    chain_kernel<<<B, 256, 0, stream>>>(actB, actA,
                                        W[2], bi[2], sl[2],
                                        W[3], bi[3], sl[3],
                                        W[4], bi[4], sl[4],
                                        W[5], bi[5], sl[5]);

    const int nbt64 = B / 64;   // 8
    const int nbt32 = B / 32;   // 16

    // L6, L7: BT=64
    {   dim3 g((LDIM[6]/2) * nbt64, LFEAT[6]/64);
        kdmfma_kernel<128, 64><<<g, 256, 0, stream>>>(actA, wqp[6], bi[6], sl[6], actB, LFEAT[6], LDIM[6], nbt64); }
    {   dim3 g((LDIM[7]/2) * nbt64, LFEAT[7]/64);
        kdmfma_kernel<256, 64><<<g, 256, 0, stream>>>(actB, wqp[7], bi[7], sl[7], actA, LFEAT[7], LDIM[7], nbt64); }

    // L8..L10: BT=32
    {   dim3 g((LDIM[8]/2) * nbt32, LFEAT[8]/64);
        kdmfma_kernel<512, 32><<<g, 256, 0, stream>>>(actA, wqp[8], bi[8], sl[8], actB, LFEAT[8], LDIM[8], nbt32); }
    {   dim3 g((LDIM[9]/2) * nbt32, LFEAT[9]/64);
        kdmfma_kernel<512, 32><<<g, 256, 0, stream>>>(actB, wqp[9], bi[9], sl[9], actA, LFEAT[9], LDIM[9], nbt32); }
    {   dim3 g((LDIM[10]/2) * nbt32, LFEAT[10]/64);
        kdmfma_kernel<512, 32><<<g, 256, 0, stream>>>(actA, wqp[10], bi[10], sl[10], actB, LFEAT[10], LDIM[10], nbt32); }

    // FC + log_softmax
    fc_lsm_kernel<<<B, 256, 0, stream>>>(actB, (const float*)d_in[34],
                                         (const float*)d_in[35], (float*)d_out);
}